// Round 3
// baseline (495.181 us; speedup 1.0000x reference)
//
#include <hip/hip_runtime.h>

#define GRID 512

// ---------------- device-scope grid barrier (persistent blocks) --------------
// Counters zeroed by hipMemsetAsync before launch (capture-safe).
// GRID=512 = 2 blocks/CU; launch_bounds(256,2) guarantees >=2 blocks/CU by
// VGPR (<=256); LDS 23.4KB allows 6/CU. Co-residency has wide margin.
__device__ __forceinline__ void grid_bar(unsigned* bar, int which) {
  __syncthreads();
  if (threadIdx.x == 0) {
    __threadfence();
    unsigned* c = bar + which * 16;  // 64B line per barrier
    atomicAdd(c, 1u);
    while (atomicAdd(c, 0u) < (unsigned)GRID) __builtin_amdgcn_s_sleep(2);
    __threadfence();
  }
  __syncthreads();
}

// ---------- 32x128 tiled GEMM body, 256 threads, 4x4 reg tile ----------
// C[m0+m, col0+n] = sum_k A[(m0+m)*lda + k] * B[k*ldb + col0 + n]
// smem: 16*36 + 16*132 = 2688 floats.
__device__ __forceinline__ void gemm32(
    float* __restrict__ smem,
    const float* __restrict__ A, int lda,
    const float* __restrict__ B, int ldb,
    float* __restrict__ C, int ldc, int K,
    int m0, int col0) {
  float* As = smem;            // [16][36] (k-major, transposed)
  float* Bs = smem + 16 * 36;  // [16][132]
  const int t = threadIdx.x;
  const int tn = t & 31, tm = t >> 5;
  const int lam = t >> 2, lak = (t & 3) * 4;  // threads 0..127 load A
  const int lbk = t >> 4, lbn = (t & 15) * 8;
  float acc[4][4];
#pragma unroll
  for (int i = 0; i < 4; ++i)
#pragma unroll
    for (int j = 0; j < 4; ++j) acc[i][j] = 0.f;
  for (int k0 = 0; k0 < K; k0 += 16) {
    if (t < 128) {
      float4 av = *reinterpret_cast<const float4*>(A + (size_t)(m0 + lam) * lda + k0 + lak);
      As[(lak + 0) * 36 + lam] = av.x;
      As[(lak + 1) * 36 + lam] = av.y;
      As[(lak + 2) * 36 + lam] = av.z;
      As[(lak + 3) * 36 + lam] = av.w;
    }
    const float* bp = B + (size_t)(k0 + lbk) * ldb + col0 + lbn;
    float4 b0 = *reinterpret_cast<const float4*>(bp);
    float4 b1 = *reinterpret_cast<const float4*>(bp + 4);
    float* bd = &Bs[lbk * 132 + lbn];
    *reinterpret_cast<float4*>(bd) = b0;
    *reinterpret_cast<float4*>(bd + 4) = b1;
    __syncthreads();
#pragma unroll
    for (int kk = 0; kk < 16; ++kk) {
      float4 a4 = *reinterpret_cast<const float4*>(&As[kk * 36 + tm * 4]);
      float4 b4 = *reinterpret_cast<const float4*>(&Bs[kk * 132 + tn * 4]);
      float a[4] = {a4.x, a4.y, a4.z, a4.w};
      float b[4] = {b4.x, b4.y, b4.z, b4.w};
#pragma unroll
      for (int i = 0; i < 4; ++i)
#pragma unroll
        for (int j = 0; j < 4; ++j) acc[i][j] = fmaf(a[i], b[j], acc[i][j]);
    }
    __syncthreads();
  }
#pragma unroll
  for (int i = 0; i < 4; ++i) {
    float* cp = C + (size_t)(m0 + tm * 4 + i) * ldc + col0 + tn * 4;
    *reinterpret_cast<float4*>(cp) =
        make_float4(acc[i][0], acc[i][1], acc[i][2], acc[i][3]);
  }
}

// ======================= GAT attention body (compile-time E) ==================
// Phase 1: load rows + per-head dot + 4x4 quad transpose-reduce (3 shfls) +
//          cross-quad butterfly -> partial[e][h].
// Phase 2: wave-parallel softmax (64 lanes over e-axis) -> alphaT[h][e].
// Phase 3: alpha preloaded to regs (float4 broadcasts); FIN=512 computes all 4
//          heads per tile read.
// smem floats: MR*FIN + MR*PP + 4*32.
template <int FIN, int TPR, int E>
__device__ __forceinline__ void gat_body(
    float* __restrict__ smem,
    const float* __restrict__ xself, const float* __restrict__ xneigh,
    const float* __restrict__ waS, const float* __restrict__ waN,
    float* __restrict__ out) {
  constexpr int MR = E + 1;
  constexpr int RPP = 256 / TPR;
  constexpr int PP = (TPR > 64) ? 8 : 4;
  constexpr int EP = 32;
  float* tile = smem;                 // MR*FIN
  float* partial = tile + MR * FIN;   // MR*PP
  float* alphaT = partial + MR * PP;  // 4*EP, [h][e]
  const int t = threadIdx.x;
  const int el = t / TPR;
  const int f0 = (t % TPR) * 4;
  float4 wn[4], ws[4];
#pragma unroll
  for (int h = 0; h < 4; ++h) {
    wn[h] = *reinterpret_cast<const float4*>(waN + h * FIN + f0);
    ws[h] = *reinterpret_cast<const float4*>(waS + h * FIN + f0);
  }
#pragma unroll
  for (int p = 0; p * RPP < MR; ++p) {
    int e = p * RPP + el;
    if (e < MR) {
      const float* src = (e < E) ? (xneigh + (size_t)e * FIN + f0) : (xself + f0);
      float4 x = *reinterpret_cast<const float4*>(src);
      *reinterpret_cast<float4*>(tile + e * FIN + f0) = x;
      float ph[4];
#pragma unroll
      for (int h = 0; h < 4; ++h) {
        float4 w = (e < E) ? wn[h] : ws[h];
        ph[h] = x.x * w.x + x.y * w.y + x.z * w.z + x.w * w.w;
      }
      // 4x4 quad transpose-reduce: lane with (t&3)==h ends with quad sum of h
      const int b0 = t & 1, b1 = (t >> 1) & 1;
      float m0 = b0 ? ph[1] : ph[0];
      float o0 = b0 ? ph[0] : ph[1];
      float m1 = b0 ? ph[3] : ph[2];
      float o1 = b0 ? ph[2] : ph[3];
      m0 += __shfl_xor(o0, 1);
      m1 += __shfl_xor(o1, 1);
      float mk = b1 ? m1 : m0;
      float gv = b1 ? m0 : m1;
      mk += __shfl_xor(gv, 2);
      mk += __shfl_xor(mk, 4);
      mk += __shfl_xor(mk, 8);
      mk += __shfl_xor(mk, 16);
      if constexpr (TPR > 64) {
        mk += __shfl_xor(mk, 32);
        if ((t & 63) < 4) partial[e * 8 + ((t >> 6) & 1) * 4 + (t & 3)] = mk;
      } else {
        if ((t & (TPR - 1)) < 4) partial[e * 4 + (t & 3)] = mk;
      }
    }
  }
  __syncthreads();
  if (t < 64) {  // wave-parallel softmax over E neighbors x 4 heads
    const int h = t & 3;
    const int e0 = t >> 2;  // 0..15
    float selfl = partial[E * PP + h];
    if constexpr (PP == 8) selfl += partial[E * PP + 4 + h];
    float x0 = -1e30f, x1 = -1e30f;
    if (e0 < E) {
      float v = partial[e0 * PP + h];
      if constexpr (PP == 8) v += partial[e0 * PP + 4 + h];
      float x = selfl + v;
      x0 = (x > 0.f) ? x : 0.2f * x;  // LeakyReLU(0.2)
    }
    if constexpr (E > 16) {
      if (e0 + 16 < E) {
        float v = partial[(e0 + 16) * PP + h];
        if constexpr (PP == 8) v += partial[(e0 + 16) * PP + 4 + h];
        float x = selfl + v;
        x1 = (x > 0.f) ? x : 0.2f * x;
      }
    }
    float m = fmaxf(x0, x1);
    m = fmaxf(m, __shfl_xor(m, 4));
    m = fmaxf(m, __shfl_xor(m, 8));
    m = fmaxf(m, __shfl_xor(m, 16));
    m = fmaxf(m, __shfl_xor(m, 32));
    float p0 = (e0 < E) ? __expf(x0 - m) : 0.f;
    float p1 = 0.f;
    if constexpr (E > 16) p1 = (e0 + 16 < E) ? __expf(x1 - m) : 0.f;
    float s = p0 + p1;
    s += __shfl_xor(s, 4);
    s += __shfl_xor(s, 8);
    s += __shfl_xor(s, 16);
    s += __shfl_xor(s, 32);
    float inv = 1.f / s;
    if (e0 < E) alphaT[h * EP + e0] = p0 * inv;
    if constexpr (E > 16)
      if (e0 + 16 < E) alphaT[h * EP + e0 + 16] = p1 * inv;
  }
  __syncthreads();
  constexpr int NQ = (E + 3) / 4;
  if constexpr (FIN == 128) {
    // thread = (head, float2 chunk); alpha in registers
    const int h = t >> 6, f = (t & 63) * 2;
    float al[NQ * 4];
#pragma unroll
    for (int q = 0; q < NQ; ++q)
      *reinterpret_cast<float4*>(&al[q * 4]) =
          *reinterpret_cast<const float4*>(&alphaT[h * EP + q * 4]);
    float2 acc = make_float2(0.f, 0.f);
#pragma unroll
    for (int e = 0; e < E; ++e) {
      float2 x = *reinterpret_cast<const float2*>(tile + e * FIN + f);
      acc.x = fmaf(al[e], x.x, acc.x);
      acc.y = fmaf(al[e], x.y, acc.y);
    }
    *reinterpret_cast<float2*>(out + h * FIN + f) = acc;
  } else {
    // thread = float2 chunk, all 4 heads per tile read (4x data reuse)
    const int f = t * 2;
    float al[4][NQ * 4];
#pragma unroll
    for (int h = 0; h < 4; ++h)
#pragma unroll
      for (int q = 0; q < NQ; ++q)
        *reinterpret_cast<float4*>(&al[h][q * 4]) =
            *reinterpret_cast<const float4*>(&alphaT[h * EP + q * 4]);
    float2 acc[4];
#pragma unroll
    for (int h = 0; h < 4; ++h) acc[h] = make_float2(0.f, 0.f);
#pragma unroll
    for (int e = 0; e < E; ++e) {
      float2 x = *reinterpret_cast<const float2*>(tile + e * FIN + f);
#pragma unroll
      for (int h = 0; h < 4; ++h) {
        acc[h].x = fmaf(al[h][e], x.x, acc[h].x);
        acc[h].y = fmaf(al[h][e], x.y, acc[h].y);
      }
    }
#pragma unroll
    for (int h = 0; h < 4; ++h)
      *reinterpret_cast<float2*>(out + h * FIN + f) = acc[h];
  }
}

// ======================= single persistent fused kernel =======================
// S0: T = W1@Wfc (head-blocked) + wa vectors
// S1: Wfinal = W0@T (128) + va (16) FIRST, then layer-0 attention (11264)
// S2: layer-1 attention in xagg space (1024)
// S3: out-gemm K-split x8 (512)
// S4: reduce
__global__ void __launch_bounds__(256, 2) gat_fused(
    const float* __restrict__ h0, const float* __restrict__ h1,
    const float* __restrict__ h2, const float* __restrict__ W0,
    const float* __restrict__ a0s, const float* __restrict__ a0n,
    const float* __restrict__ W1, const float* __restrict__ a1s,
    const float* __restrict__ a1n, const float* __restrict__ Wfc,
    float* __restrict__ wsb, float* __restrict__ out,
    unsigned* __restrict__ bar) {
  __shared__ float smem[5848];  // max: gat<512,..>: 11*512+88+128
  const int bid = blockIdx.x;
  const int t = threadIdx.x;

  float* wa0s = wsb;                  // [4][128]
  float* wa0n = wa0s + 512;           // [4][128]
  float* wa1s = wa0n + 512;           // [4][512]
  float* wa1n = wa1s + 2048;          // [4][512]
  float* va1s = wa1n + 2048;          // [4][4][128]
  float* va1n = va1s + 2048;          // [4][4][128]
  float* T = va1n + 2048;             // [4][512][256] = 524288
  float* Wfinal = T + 524288;         // [4][512][256] = 524288
  float* xagg = Wfinal + 524288;      // [11264][512]  = 5767168
  float* aggx = xagg + 5767168;       // [1024][2048]  = 2097152
  float* Cpart = xagg;                // [8][1024][256] aliased (xagg dead by S3)

  // ---- S0: T gemm (128 items) + wa vectors (20 items); 148 < GRID ----
  if (bid < 128) {
    int h = bid >> 5, mb = (bid >> 1) & 15, nb = bid & 1;
    gemm32(smem, W1 + h * 128, 512, Wfc + (size_t)h * 32768, 256,
           T + (size_t)h * 131072, 256, 128, mb * 32, nb * 128);
  } else if (bid < 148) {
    int idx = (bid - 128) * 256 + t;  // < 5120
    const float* W; const float* a; float* dst; int i; int FINW;
    if (idx < 512)       { W = W0; a = a0s; dst = wa0s; i = idx;        FINW = 128; }
    else if (idx < 1024) { W = W0; a = a0n; dst = wa0n; i = idx - 512;  FINW = 128; }
    else if (idx < 3072) { W = W1; a = a1s; dst = wa1s; i = idx - 1024; FINW = 512; }
    else                 { W = W1; a = a1n; dst = wa1n; i = idx - 3072; FINW = 512; }
    int f = i >> 2, hh = i & 3;
    const float* wrow = W + (size_t)f * 512 + hh * 128;
    const float* arow = a + hh * 128;
    float v = 0.f;
#pragma unroll 8
    for (int d = 0; d < 128; ++d) v = fmaf(wrow[d], arow[d], v);
    dst[hh * FINW + f] = v;
  }
  grid_bar(bar, 0);

  // ---- S1: 11408 items; gemm/va first (overlap), then attention ----
  for (int i = bid; i < 11408; i += GRID) {
    if (i < 128) {
      int h = i >> 5, h0b = (i >> 3) & 3, mb = (i >> 1) & 3, nb = i & 1;
      gemm32(smem, W0 + h0b * 128, 512,
             T + (size_t)h * 131072 + (size_t)h0b * 32768, 256,
             Wfinal + (size_t)h * 131072 + (size_t)h0b * 32768, 256, 128,
             mb * 32, nb * 128);
    } else if (i < 144) {
      int idx = (i - 128) * 256 + t;  // < 4096
      const float* wa = (idx < 2048) ? wa1s : wa1n;
      float* dst = (idx < 2048) ? va1s : va1n;
      int j = idx & 2047;
      int hh = j >> 9, h0b = (j >> 7) & 3, f = j & 127;
      const float* w0row = W0 + (size_t)f * 512 + h0b * 128;
      const float* warow = wa + hh * 512 + h0b * 128;
      float v = 0.f;
#pragma unroll 8
      for (int n = 0; n < 128; ++n) v = fmaf(w0row[n], warow[n], v);
      dst[j] = v;
    } else if (i < 144 + 10240) {
      int g = i - 144;
      gat_body<128, 32, 25>(smem, h1 + (size_t)g * 128, h2 + (size_t)g * 3200,
                            wa0s, wa0n, xagg + (size_t)(1024 + g) * 512);
    } else {
      int n = i - 10384;
      gat_body<128, 32, 10>(smem, h0 + (size_t)n * 128, h1 + (size_t)n * 1280,
                            wa0s, wa0n, xagg + (size_t)n * 512);
    }
    __syncthreads();  // smem reuse across items
  }
  grid_bar(bar, 1);

  // ---- S2: layer-1 attention, 1024 items over GRID blocks ----
  for (int ii = bid; ii < 1024; ii += GRID) {
    gat_body<512, 128, 10>(smem, xagg + (size_t)ii * 512,
                           xagg + (size_t)(1024 + ii * 10) * 512, va1s, va1n,
                           aggx + (size_t)ii * 2048);
    __syncthreads();
  }
  grid_bar(bar, 2);

  // ---- S3: out-gemm K-split x8: 8 ks x 32 mb x 2 nb = 512 items ----
  {
    int ks = bid >> 6, mb = (bid >> 1) & 31, nb = bid & 1;
    gemm32(smem, aggx + ks * 256, 2048, Wfinal + (size_t)ks * 65536, 256,
           Cpart + (size_t)ks * 262144, 256, 256, mb * 32, nb * 128);
  }
  grid_bar(bar, 3);

  // ---- S4: reduce 8 partials; 65536 float4 over 512 blocks x 128 lanes ----
  if (t < 128) {
    int i = (bid << 7) + t;
    const float4* p = reinterpret_cast<const float4*>(Cpart) + i;
    float4 s = p[0];
#pragma unroll
    for (int ks = 1; ks < 8; ++ks) {
      float4 v = p[(size_t)ks * 65536];
      s.x += v.x; s.y += v.y; s.z += v.z; s.w += v.w;
    }
    reinterpret_cast<float4*>(out)[i] = s;
  }
}

extern "C" void kernel_launch(void* const* d_in, const int* in_sizes, int n_in,
                              void* d_out, int out_size, void* d_ws, size_t ws_size,
                              hipStream_t stream) {
  const float* h0  = (const float*)d_in[0];
  const float* h1  = (const float*)d_in[1];
  const float* h2  = (const float*)d_in[2];
  const float* W0  = (const float*)d_in[3];
  const float* a0s = (const float*)d_in[4];
  const float* a0n = (const float*)d_in[5];
  const float* W1  = (const float*)d_in[6];
  const float* a1s = (const float*)d_in[7];
  const float* a1n = (const float*)d_in[8];
  const float* Wfc = (const float*)d_in[9];

  float* ws = (float*)d_ws;
  // float usage: 9216 small + 2*524288 + 5767168 + 2097152 = 8922112 (35.7 MB)
  // (Cpart aliases xagg; xagg is dead after S2.)
  unsigned* bar = (unsigned*)(ws + 8922112);
  hipMemsetAsync(bar, 0, 256, stream);
  gat_fused<<<GRID, 256, 0, stream>>>(h0, h1, h2, W0, a0s, a0n, W1, a1s, a1n,
                                      Wfc, ws, (float*)d_out, bar);
}